// Round 1
// baseline (306.651 us; speedup 1.0000x reference)
//
#include <hip/hip_runtime.h>
#include <hip/hip_bf16.h>

#define NROWS 8192
#define DIM   256
#define MARGIN 0.3f

using bf16x8 = __attribute__((ext_vector_type(8))) short;
using f32x4  = __attribute__((ext_vector_type(4))) float;

__device__ inline ushort f2bf(float f) {
    __hip_bfloat16 h = __float2bfloat16(f);
    return *reinterpret_cast<ushort*>(&h);
}
__device__ inline float bf2f(ushort u) {
    return __uint_as_float(((unsigned)u) << 16);
}

// One wave per row: L2-normalize in fp32, round to bf16, store bf16 row,
// store sum of squares of the *rounded* values (so d2 = ||x_i - x_j||^2 >= 0
// up to MFMA accumulation rounding). Also initializes the atomic reduce arrays.
__global__ __launch_bounds__(256) void norm_kernel(
    const float* __restrict__ in, ushort* __restrict__ xb,
    float* __restrict__ sq, unsigned* __restrict__ pmax2,
    unsigned* __restrict__ nmin2)
{
    int row  = blockIdx.x * 4 + (threadIdx.x >> 6);
    int lane = threadIdx.x & 63;
    float4 v = ((const float4*)(in + (size_t)row * DIM))[lane];
    float ss = v.x * v.x + v.y * v.y + v.z * v.z + v.w * v.w;
#pragma unroll
    for (int m = 1; m < 64; m <<= 1) ss += __shfl_xor(ss, m, 64);
    float inv = 1.0f / (sqrtf(ss) + 1e-12f);

    ushort4 st;
    st.x = f2bf(v.x * inv); st.y = f2bf(v.y * inv);
    st.z = f2bf(v.z * inv); st.w = f2bf(v.w * inv);
    ((ushort4*)(xb + (size_t)row * DIM))[lane] = st;

    float a0 = bf2f(st.x), a1 = bf2f(st.y), a2 = bf2f(st.z), a3 = bf2f(st.w);
    float s2 = a0 * a0 + a1 * a1 + a2 * a2 + a3 * a3;
#pragma unroll
    for (int m = 1; m < 64; m <<= 1) s2 += __shfl_xor(s2, m, 64);
    if (lane == 0) {
        sq[row]    = s2;
        pmax2[row] = 0u;           // max of d2 over positives (d2 >= 0)
        nmin2[row] = 0x7F800000u;  // +inf: min of d2 over negatives
    }
}

// Fused gram + masked hard-pos/hard-neg reduction.
// Block = 4 waves; each wave owns 16 rows (all K=256 of A preloaded in 32 VGPRs).
// Block covers 64 rows x 1024 cols; grid = (8192/64, 8192/1024).
// C/D layout (verified m89/m91): col = lane&15, row = quad*4 + reg.
// A layout: A[m = lane&15][k = quad*8 + j]; B (B^T form) loads identically.
__global__ __launch_bounds__(256) void gram_kernel(
    const ushort* __restrict__ xb, const float* __restrict__ sq,
    const int* __restrict__ tgt, unsigned* __restrict__ pmax2,
    unsigned* __restrict__ nmin2)
{
    const int wave = threadIdx.x >> 6;
    const int lane = threadIdx.x & 63;
    const int l15  = lane & 15;
    const int quad = lane >> 4;
    const int m0   = blockIdx.x * 64 + wave * 16;  // wave's row base
    const int nb   = blockIdx.y * 1024;            // block's col base

    // Preload A fragments: rows m0+l15, k = k0 + quad*8 .. +7
    bf16x8 afrag[8];
    const ushort* arow = xb + (size_t)(m0 + l15) * DIM + quad * 8;
#pragma unroll
    for (int kk = 0; kk < 8; ++kk)
        afrag[kk] = *(const bf16x8*)(arow + kk * 32);

    // Per-lane row metadata: rows m0 + quad*4 + i
    float sqi[4]; int ti[4];
#pragma unroll
    for (int i = 0; i < 4; ++i) {
        int r = m0 + quad * 4 + i;
        sqi[i] = sq[r];
        ti[i]  = tgt[r];
    }

    float pm[4] = {0.f, 0.f, 0.f, 0.f};
    float nm[4] = {INFINITY, INFINITY, INFINITY, INFINITY};

    for (int t = 0; t < 64; ++t) {
        const int n0 = nb + t * 16;
        const ushort* brow = xb + (size_t)(n0 + l15) * DIM + quad * 8;
        f32x4 acc = {0.f, 0.f, 0.f, 0.f};
#pragma unroll
        for (int kk = 0; kk < 8; ++kk) {
            bf16x8 bfrag = *(const bf16x8*)(brow + kk * 32);
            acc = __builtin_amdgcn_mfma_f32_16x16x32_bf16(afrag[kk], bfrag, acc, 0, 0, 0);
        }
        const int   tc  = tgt[n0 + l15];
        const float sqc = sq[n0 + l15];
        const bool diagTile = (n0 == m0);  // wave-uniform
#pragma unroll
        for (int i = 0; i < 4; ++i) {
            float d2 = fmaf(acc[i], -2.0f, sqi[i] + sqc);
            d2 = fmaxf(d2, 0.0f);
            const bool same   = (ti[i] == tc);
            const bool isdiag = diagTile && ((quad * 4 + i) == l15);
            float dp = (same && !isdiag) ? d2 : -1.0f;   // positives
            pm[i] = fmaxf(pm[i], dp);
            float dn = same ? INFINITY : d2;             // negatives
            nm[i] = fminf(nm[i], dn);
        }
    }

    // Reduce over the 16 columns held by lanes of the same quad
#pragma unroll
    for (int m = 1; m < 16; m <<= 1) {
#pragma unroll
        for (int i = 0; i < 4; ++i) {
            pm[i] = fmaxf(pm[i], __shfl_xor(pm[i], m, 64));
            nm[i] = fminf(nm[i], __shfl_xor(nm[i], m, 64));
        }
    }
    if (l15 == 0) {
#pragma unroll
        for (int i = 0; i < 4; ++i) {
            int r = m0 + quad * 4 + i;
            atomicMax(&pmax2[r], __float_as_uint(fmaxf(pm[i], 0.0f)));
            atomicMin(&nmin2[r], __float_as_uint(nm[i]));
        }
    }
}

// Final hinge + mean in fp64 (fp32 atomic accumulation would be too lossy
// vs the 0.011 absolute threshold).
__global__ __launch_bounds__(256) void finalize_kernel(
    const unsigned* __restrict__ pmax2, const unsigned* __restrict__ nmin2,
    float* __restrict__ out)
{
    double s = 0.0;
    for (int r = threadIdx.x; r < NROWS; r += 256) {
        float pm = __uint_as_float(pmax2[r]);
        float nmv = __uint_as_float(nmin2[r]);
        // no positives -> pm==0 -> ap = 1e-6 ~= ref 0.0 (diff negligible)
        float ap = sqrtf(fmaxf(pm, 1e-12f));
        float an = (nmv > 1e37f) ? (MARGIN + 1.0f) : sqrtf(fmaxf(nmv, 1e-12f));
        float h  = ap - an + MARGIN;
        s += (h > 0.0f) ? (double)h : 0.0;
    }
    __shared__ double sh[256];
    sh[threadIdx.x] = s;
    __syncthreads();
    for (int ofs = 128; ofs > 0; ofs >>= 1) {
        if (threadIdx.x < ofs) sh[threadIdx.x] += sh[threadIdx.x + ofs];
        __syncthreads();
    }
    if (threadIdx.x == 0) out[0] = (float)(sh[0] / (double)NROWS);
}

extern "C" void kernel_launch(void* const* d_in, const int* in_sizes, int n_in,
                              void* d_out, int out_size, void* d_ws, size_t ws_size,
                              hipStream_t stream) {
    const float* in  = (const float*)d_in[0];
    const int*   tgt = (const int*)d_in[1];
    float*       out = (float*)d_out;

    char* ws = (char*)d_ws;
    ushort*   xb    = (ushort*)ws;                                  // 8192*256*2 = 4 MB
    float*    sq    = (float*)(ws + (size_t)NROWS * DIM * 2);       // 32 KB
    unsigned* pmax2 = (unsigned*)(ws + (size_t)NROWS * DIM * 2 + NROWS * 4);
    unsigned* nmin2 = (unsigned*)(ws + (size_t)NROWS * DIM * 2 + NROWS * 8);

    norm_kernel<<<NROWS / 4, 256, 0, stream>>>(in, xb, sq, pmax2, nmin2);
    gram_kernel<<<dim3(NROWS / 64, NROWS / 1024), 256, 0, stream>>>(xb, sq, tgt, pmax2, nmin2);
    finalize_kernel<<<1, 256, 0, stream>>>(pmax2, nmin2, out);
}

// Round 2
// 163.800 us; speedup vs baseline: 1.8721x; 1.8721x over previous
//
#include <hip/hip_runtime.h>
#include <hip/hip_bf16.h>

#define NROWS 8192
#define DIM   256
#define MARGIN 0.3f

using bf16x8 = __attribute__((ext_vector_type(8))) short;
using f32x4  = __attribute__((ext_vector_type(4))) float;

__device__ inline ushort f2bf(float f) {
    __hip_bfloat16 h = __float2bfloat16(f);
    return *reinterpret_cast<ushort*>(&h);
}
__device__ inline float bf2f(ushort u) {
    return __uint_as_float(((unsigned)u) << 16);
}
// Order-preserving float<->uint transform so bitwise atomicMax/Min implement
// signed-float max/min (values sqc - 2*acc can be negative; sentinels are +-inf).
__device__ inline unsigned f2ord(float f) {
    unsigned b = __float_as_uint(f);
    return (b & 0x80000000u) ? ~b : (b | 0x80000000u);
}
__device__ inline float ord2f(unsigned u) {
    return __uint_as_float((u & 0x80000000u) ? (u & 0x7FFFFFFFu) : ~u);
}

// One wave per row: L2-normalize in fp32, round to bf16, store bf16 row and
// the sum of squares of the *rounded* row. Init the ordered-atomic arrays:
// pmax = ord(-inf)  (max over positives of sqc-2acc),
// nmin = ord(+inf)  (min over negatives of sqc-2acc).
__global__ __launch_bounds__(256) void norm_kernel(
    const float* __restrict__ in, ushort* __restrict__ xb,
    float* __restrict__ sq, unsigned* __restrict__ pmax,
    unsigned* __restrict__ nmin)
{
    int row  = blockIdx.x * 4 + (threadIdx.x >> 6);
    int lane = threadIdx.x & 63;
    float4 v = ((const float4*)(in + (size_t)row * DIM))[lane];
    float ss = v.x * v.x + v.y * v.y + v.z * v.z + v.w * v.w;
#pragma unroll
    for (int m = 1; m < 64; m <<= 1) ss += __shfl_xor(ss, m, 64);
    float inv = 1.0f / (sqrtf(ss) + 1e-12f);

    ushort4 st;
    st.x = f2bf(v.x * inv); st.y = f2bf(v.y * inv);
    st.z = f2bf(v.z * inv); st.w = f2bf(v.w * inv);
    ((ushort4*)(xb + (size_t)row * DIM))[lane] = st;

    float a0 = bf2f(st.x), a1 = bf2f(st.y), a2 = bf2f(st.z), a3 = bf2f(st.w);
    float s2 = a0 * a0 + a1 * a1 + a2 * a2 + a3 * a3;
#pragma unroll
    for (int m = 1; m < 64; m <<= 1) s2 += __shfl_xor(s2, m, 64);
    if (lane == 0) {
        sq[row]   = s2;
        pmax[row] = 0x007FFFFFu;  // f2ord(-inf)
        nmin[row] = 0xFF800000u;  // f2ord(+inf)
    }
}

// Fused gram + masked hard-pos/hard-neg reduction, 4 A-tiles per wave.
// Block = 4 waves, wave owns 64 rows (4 x 16-row tiles, full K=256 in regs).
// Grid (32,16): x = 256-row block, y = 512-col chunk (32 col-tiles inner loop).
// We track e = sqc - 2*<xi,xj>; row-constant sqi is added in finalize
// (max/min commute with adding a row constant).
// Diagonal is NOT excluded: self e = -sqi => d2 ~ 0, cannot win the positive
// max (true positive pairs in random 256-d data have d2 ~ 2).
// C/D layout: col = lane&15, row = quad*4 + reg (verified m89/m91).
__global__ __launch_bounds__(256, 2) void gram_kernel(
    const ushort* __restrict__ xb, const float* __restrict__ sq,
    const int* __restrict__ tgt, unsigned* __restrict__ pmax,
    unsigned* __restrict__ nmin)
{
    const int wave = threadIdx.x >> 6;
    const int lane = threadIdx.x & 63;
    const int l15  = lane & 15;
    const int quad = lane >> 4;
    const int mbase = blockIdx.x * 256 + wave * 64;  // wave's 64-row base
    const int nbase = blockIdx.y * 512;              // block's 512-col chunk

    // Preload A fragments: tile a, rows mbase + a*16 + l15, k = quad*8 + kk*32 + j
    bf16x8 afrag[4][8];
#pragma unroll
    for (int a = 0; a < 4; ++a) {
        const ushort* arow = xb + (size_t)(mbase + a * 16 + l15) * DIM + quad * 8;
#pragma unroll
        for (int kk = 0; kk < 8; ++kk)
            afrag[a][kk] = *(const bf16x8*)(arow + kk * 32);
    }

    // Row targets for the C elements this lane owns: row = mbase + a*16 + quad*4 + i
    int ti[16];
#pragma unroll
    for (int a = 0; a < 4; ++a)
#pragma unroll
        for (int i = 0; i < 4; ++i)
            ti[a * 4 + i] = tgt[mbase + a * 16 + quad * 4 + i];

    float pm[16], nm[16];
#pragma unroll
    for (int j = 0; j < 16; ++j) { pm[j] = -__builtin_inff(); nm[j] = __builtin_inff(); }

    for (int t = 0; t < 32; ++t) {
        const int n0 = nbase + t * 16;
        const ushort* brow = xb + (size_t)(n0 + l15) * DIM + quad * 8;
        bf16x8 bfrag[8];
#pragma unroll
        for (int kk = 0; kk < 8; ++kk)
            bfrag[kk] = *(const bf16x8*)(brow + kk * 32);
        const float sqc = sq[n0 + l15];
        const int   tc  = tgt[n0 + l15];

#pragma unroll
        for (int a = 0; a < 4; ++a) {
            f32x4 acc = {0.f, 0.f, 0.f, 0.f};
#pragma unroll
            for (int kk = 0; kk < 8; ++kk)
                acc = __builtin_amdgcn_mfma_f32_16x16x32_bf16(afrag[a][kk], bfrag[kk], acc, 0, 0, 0);
#pragma unroll
            for (int i = 0; i < 4; ++i) {
                const float v = fmaf(acc[i], -2.0f, sqc);
                const bool same = (ti[a * 4 + i] == tc);
                pm[a * 4 + i] = fmaxf(pm[a * 4 + i], same ? v : -__builtin_inff());
                nm[a * 4 + i] = fminf(nm[a * 4 + i], same ? __builtin_inff() : v);
            }
        }
    }

    // Reduce over the 16 columns (l15 groups); row identity lives in (quad, a, i)
#pragma unroll
    for (int m = 1; m < 16; m <<= 1) {
#pragma unroll
        for (int j = 0; j < 16; ++j) {
            pm[j] = fmaxf(pm[j], __shfl_xor(pm[j], m, 64));
            nm[j] = fminf(nm[j], __shfl_xor(nm[j], m, 64));
        }
    }
    if (l15 == 0) {
#pragma unroll
        for (int a = 0; a < 4; ++a)
#pragma unroll
            for (int i = 0; i < 4; ++i) {
                int r = mbase + a * 16 + quad * 4 + i;
                atomicMax(&pmax[r], f2ord(pm[a * 4 + i]));
                atomicMin(&nmin[r], f2ord(nm[a * 4 + i]));
            }
    }
}

// Final: ap = sqrt(max(sq[r] + e_p, 0)), an = sqrt(max(sq[r] + e_n, 0)),
// hinge + mean in fp64.
__global__ __launch_bounds__(256) void finalize_kernel(
    const unsigned* __restrict__ pmax, const unsigned* __restrict__ nmin,
    const float* __restrict__ sq, float* __restrict__ out)
{
    double s = 0.0;
    for (int r = threadIdx.x; r < NROWS; r += 256) {
        float pe = ord2f(pmax[r]);
        float ne = ord2f(nmin[r]);
        float ap = (pe < -1e30f) ? 0.0f : sqrtf(fmaxf(sq[r] + pe, 0.0f));
        float an = (ne >  1e30f) ? (MARGIN + 1.0f) : sqrtf(fmaxf(sq[r] + ne, 0.0f));
        float h  = ap - an + MARGIN;
        s += (h > 0.0f) ? (double)h : 0.0;
    }
    __shared__ double sh[256];
    sh[threadIdx.x] = s;
    __syncthreads();
    for (int ofs = 128; ofs > 0; ofs >>= 1) {
        if (threadIdx.x < ofs) sh[threadIdx.x] += sh[threadIdx.x + ofs];
        __syncthreads();
    }
    if (threadIdx.x == 0) out[0] = (float)(sh[0] / (double)NROWS);
}

extern "C" void kernel_launch(void* const* d_in, const int* in_sizes, int n_in,
                              void* d_out, int out_size, void* d_ws, size_t ws_size,
                              hipStream_t stream) {
    const float* in  = (const float*)d_in[0];
    const int*   tgt = (const int*)d_in[1];
    float*       out = (float*)d_out;

    char* ws = (char*)d_ws;
    ushort*   xb   = (ushort*)ws;                                   // 8192*256*2 = 4 MB
    float*    sq   = (float*)(ws + (size_t)NROWS * DIM * 2);        // 32 KB
    unsigned* pmax = (unsigned*)(ws + (size_t)NROWS * DIM * 2 + NROWS * 4);
    unsigned* nmin = (unsigned*)(ws + (size_t)NROWS * DIM * 2 + NROWS * 8);

    norm_kernel<<<NROWS / 4, 256, 0, stream>>>(in, xb, sq, pmax, nmin);
    gram_kernel<<<dim3(32, 16), 256, 0, stream>>>(xb, sq, tgt, pmax, nmin);
    finalize_kernel<<<1, 256, 0, stream>>>(pmax, nmin, sq, out);
}

// Round 3
// 113.870 us; speedup vs baseline: 2.6930x; 1.4385x over previous
//
#include <hip/hip_runtime.h>
#include <hip/hip_bf16.h>

#define NROWS  8192
#define DIM    256
#define NCLASS 512
#define MARGIN 0.3f

using bf16x8 = __attribute__((ext_vector_type(8))) short;
using f32x4  = __attribute__((ext_vector_type(4))) float;

__device__ inline ushort f2bf(float f) {
    __hip_bfloat16 h = __float2bfloat16(f);
    return *reinterpret_cast<ushort*>(&h);
}
__device__ inline float bf2f(ushort u) {
    return __uint_as_float(((unsigned)u) << 16);
}
// Order-preserving float<->uint transform: bitwise atomicMax/Min == float max/min.
__device__ inline unsigned f2ord(float f) {
    unsigned b = __float_as_uint(f);
    return (b & 0x80000000u) ? ~b : (b | 0x80000000u);
}
__device__ inline float ord2f(unsigned u) {
    return __uint_as_float((u & 0x80000000u) ? (u & 0x7FFFFFFFu) : ~u);
}
// Async global->LDS, 16B per lane. LDS dest is wave-uniform base + lane*16.
__device__ inline void ld16_g2l(const void* g, void* l) {
    __builtin_amdgcn_global_load_lds(
        (const __attribute__((address_space(1))) unsigned int*)g,
        (__attribute__((address_space(3))) unsigned int*)l, 16, 0, 0);
}

// ---- workspace layout (bytes) ----
#define XBS_OFF 0u            // 8192*256*2 = 4194304  sorted bf16 rows
#define SQS_OFF 4194304u      // 32768  sorted ||x||^2
#define TGT_OFF 4227072u      // 32768  sorted targets (int)
#define PMX_OFF 4259840u      // 32768  ordered-uint max over positives of (sqc-2acc)
#define NMN_OFF 4292608u      // 32768  ordered-uint min over negatives
#define BIN_OFF 4325376u      // 2048   class bin cursors
#define ACC_OFF 4327424u      // 8      double loss accumulator
#define TIK_OFF 4327432u      // 4      completion ticket

// K1: one block. Histogram of targets -> exclusive scan -> bin cursors.
// Also zeros the fp64 accumulator and the ticket.
__global__ __launch_bounds__(512) void hist_scan_kernel(
    const int* __restrict__ tgt, int* __restrict__ bincur,
    double* __restrict__ accd, unsigned* __restrict__ ticket)
{
    __shared__ int h[NCLASS];
    int tid = threadIdx.x;
    h[tid] = 0;
    if (tid == 0) { *accd = 0.0; *ticket = 0u; }
    __syncthreads();
    for (int k = 0; k < NROWS / NCLASS; ++k)
        atomicAdd(&h[tgt[tid + k * NCLASS]], 1);
    __syncthreads();
    int cnt = h[tid];
    // inclusive Hillis-Steele scan
    for (int ofs = 1; ofs < NCLASS; ofs <<= 1) {
        int v = (tid >= ofs) ? h[tid - ofs] : 0;
        __syncthreads();
        h[tid] += v;
        __syncthreads();
    }
    bincur[tid] = h[tid] - cnt;  // exclusive start of class tid
}

// K2: one wave per row. Normalize fp32 -> bf16, scatter to class-sorted slot.
__global__ __launch_bounds__(256) void norm_scatter_kernel(
    const float* __restrict__ in, const int* __restrict__ tgt,
    int* __restrict__ bincur, ushort* __restrict__ xbs,
    float* __restrict__ sqs, int* __restrict__ tgts,
    unsigned* __restrict__ pmax, unsigned* __restrict__ nmin)
{
    int row  = blockIdx.x * 4 + (threadIdx.x >> 6);
    int lane = threadIdx.x & 63;
    float4 v = ((const float4*)(in + (size_t)row * DIM))[lane];
    float ss = v.x * v.x + v.y * v.y + v.z * v.z + v.w * v.w;
#pragma unroll
    for (int m = 1; m < 64; m <<= 1) ss += __shfl_xor(ss, m, 64);
    float inv = 1.0f / (sqrtf(ss) + 1e-12f);

    ushort4 st;
    st.x = f2bf(v.x * inv); st.y = f2bf(v.y * inv);
    st.z = f2bf(v.z * inv); st.w = f2bf(v.w * inv);

    int t = 0, dst = 0;
    if (lane == 0) { t = tgt[row]; dst = atomicAdd(&bincur[t], 1); }
    dst = __shfl(dst, 0); t = __shfl(t, 0);

    ((ushort4*)(xbs + (size_t)dst * DIM))[lane] = st;

    float a0 = bf2f(st.x), a1 = bf2f(st.y), a2 = bf2f(st.z), a3 = bf2f(st.w);
    float s2 = a0 * a0 + a1 * a1 + a2 * a2 + a3 * a3;
#pragma unroll
    for (int m = 1; m < 64; m <<= 1) s2 += __shfl_xor(s2, m, 64);
    if (lane == 0) {
        sqs[dst]  = s2;
        tgts[dst] = t;
        pmax[dst] = 0x007FFFFFu;  // f2ord(-inf)
        nmin[dst] = 0xFF800000u;  // f2ord(+inf)
    }
}

// K3: fused gram + hard-pos/hard-neg. Block: 4 waves, 256 rows x 512 cols.
// B staged in LDS (double-buffered, 32 cols = 16KB per stage), shared by all
// 4 waves; XOR-swizzled layout for bank-balanced ds_read_b128. Prefetch of
// stage s+1 is issued at the TOP of stage s, so the __syncthreads() vmcnt
// drain at stage end is free (loads landed ~1400 cyc earlier).
// Rows/cols are class-sorted: tiles whose class ranges don't overlap the
// wave's row classes take a 2-op/element epilogue (no positives possible).
__global__ __launch_bounds__(256, 2) void gram_kernel(
    const ushort* __restrict__ xbs, const float* __restrict__ sqs,
    const int* __restrict__ tgts, unsigned* __restrict__ pmax,
    unsigned* __restrict__ nmin)
{
    __shared__ struct {
        char  buf[2][16384];   // B stage buffers: 32 cols x 512B, swizzled
        float sqc[512];        // per-col ||x||^2 for this 512-col chunk
        int   tgc[512];        // per-col class
        int   tga[256];        // per-row class for this block's 256 rows
    } sm;

    const int wave = threadIdx.x >> 6;
    const int lane = threadIdx.x & 63;
    const int l15  = lane & 15;
    const int quad = lane >> 4;
    const int mbase = blockIdx.x * 256 + wave * 64;
    const int nbase = blockIdx.y * 512;

    // Stage per-chunk metadata into LDS (once).
    {
        int c = threadIdx.x * 2;
        sm.sqc[c]     = sqs[nbase + c];
        sm.sqc[c + 1] = sqs[nbase + c + 1];
        sm.tgc[c]     = tgts[nbase + c];
        sm.tgc[c + 1] = tgts[nbase + c + 1];
        sm.tga[threadIdx.x] = tgts[blockIdx.x * 256 + threadIdx.x];
    }

    // Preload A fragments: 4 tiles x full K=256.
    bf16x8 afrag[4][8];
#pragma unroll
    for (int a = 0; a < 4; ++a) {
        const ushort* arow = xbs + (size_t)(mbase + a * 16 + l15) * DIM + quad * 8;
#pragma unroll
        for (int kk = 0; kk < 8; ++kk)
            afrag[a][kk] = *(const bf16x8*)(arow + kk * 32);
    }
    const int rlo = tgts[mbase];       // sorted => wave row-class range
    const int rhi = tgts[mbase + 63];

    // Per-lane global source offsets for staging (xor-swizzle compensation).
    // Stage instr i writes LDS [i*1024,(i+1)*1024): col=2i+(lane>>5), slot=lane&31,
    // which must hold logical chunk c = slot ^ (col&7).
    const int colh = lane >> 5, c31 = lane & 31;
    int offs[4];
#pragma unroll
    for (int j = 0; j < 4; ++j)
        offs[j] = colh * 512 + ((c31 ^ ((2 * j + colh) & 7)) << 4);

    const char* xbs_b = (const char*)xbs;

    // Prologue: issue stage 0.
    {
        const char* gbase = xbs_b + (size_t)nbase * 512;
#pragma unroll
        for (int j = 0; j < 4; ++j) {
            int i = wave * 4 + j;
            ld16_g2l(gbase + i * 1024 + offs[j], sm.buf[0] + i * 1024);
        }
    }
    __syncthreads();  // drains prologue DMA + metadata writes

    float pm[16], nm[16];
#pragma unroll
    for (int j = 0; j < 16; ++j) { pm[j] = -__builtin_inff(); nm[j] = __builtin_inff(); }

#pragma unroll 2
    for (int s = 0; s < 16; ++s) {
        // Issue stage s+1 into the other buffer (free: everyone done reading it).
        if (s < 15) {
            const char* gbase = xbs_b + (size_t)(nbase + (s + 1) * 32) * 512;
            char* lbase = sm.buf[(s + 1) & 1];
#pragma unroll
            for (int j = 0; j < 4; ++j) {
                int i = wave * 4 + j;
                ld16_g2l(gbase + i * 1024 + offs[j], lbase + i * 1024);
            }
        }
        // Compute the two 16-col tiles of the current buffer.
        const char* bufc = sm.buf[s & 1];
#pragma unroll
        for (int u = 0; u < 2; ++u) {
            const int t16 = s * 32 + u * 16;
            bf16x8 bfrag[8];
#pragma unroll
            for (int kk = 0; kk < 8; ++kk)
                bfrag[kk] = *(const bf16x8*)(bufc + u * 8192 + l15 * 512 +
                                             (((quad + 4 * kk) ^ (l15 & 7)) << 4));
            f32x4 acc4[4];
#pragma unroll
            for (int a = 0; a < 4; ++a) {
                f32x4 acc = {0.f, 0.f, 0.f, 0.f};
#pragma unroll
                for (int kk = 0; kk < 8; ++kk)
                    acc = __builtin_amdgcn_mfma_f32_16x16x32_bf16(afrag[a][kk], bfrag[kk], acc, 0, 0, 0);
                acc4[a] = acc;
            }
            const float sqc = sm.sqc[t16 + l15];
            const int clo = sm.tgc[t16], chi = sm.tgc[t16 + 15];
            if (rlo <= chi && clo <= rhi) {
                // slow path: tile may contain positives
                const int tc = sm.tgc[t16 + l15];
#pragma unroll
                for (int a = 0; a < 4; ++a)
#pragma unroll
                    for (int i = 0; i < 4; ++i) {
                        const float v = fmaf(acc4[a][i], -2.0f, sqc);
                        const bool same = (sm.tga[wave * 64 + a * 16 + quad * 4 + i] == tc);
                        pm[a * 4 + i] = fmaxf(pm[a * 4 + i], same ? v : -__builtin_inff());
                        nm[a * 4 + i] = fminf(nm[a * 4 + i], same ? __builtin_inff() : v);
                    }
            } else {
                // fast path: negatives only
#pragma unroll
                for (int a = 0; a < 4; ++a)
#pragma unroll
                    for (int i = 0; i < 4; ++i)
                        nm[a * 4 + i] = fminf(nm[a * 4 + i], fmaf(acc4[a][i], -2.0f, sqc));
            }
        }
        __syncthreads();  // stage-s+1 DMA landed long ago -> drain is ~free
    }

    // Reduce across the 16 column-lanes (same quad), then one atomic per row.
#pragma unroll
    for (int m = 1; m < 16; m <<= 1) {
#pragma unroll
        for (int j = 0; j < 16; ++j) {
            pm[j] = fmaxf(pm[j], __shfl_xor(pm[j], m, 64));
            nm[j] = fminf(nm[j], __shfl_xor(nm[j], m, 64));
        }
    }
    if (l15 == 0) {
#pragma unroll
        for (int a = 0; a < 4; ++a)
#pragma unroll
            for (int i = 0; i < 4; ++i) {
                int r = mbase + a * 16 + quad * 4 + i;
                atomicMax(&pmax[r], f2ord(pm[a * 4 + i]));
                atomicMin(&nmin[r], f2ord(nm[a * 4 + i]));
            }
    }
}

// K4: multi-block finalize with fp64 atomic accumulation + completion ticket.
// Note: self-pair is included as a "positive" (d2_self ~ 0, never wins unless
// the class is a singleton, where ap ~ 0 matches the reference fallback).
__global__ __launch_bounds__(256) void finalize_kernel(
    const unsigned* __restrict__ pmax, const unsigned* __restrict__ nmin,
    const float* __restrict__ sqs, double* __restrict__ accd,
    unsigned* __restrict__ ticket, float* __restrict__ out)
{
    int r = blockIdx.x * 256 + threadIdx.x;
    float pe = ord2f(pmax[r]);
    float ne = ord2f(nmin[r]);
    float ap = sqrtf(fmaxf(sqs[r] + pe, 0.0f));
    float an = (ne > 1e30f) ? (MARGIN + 1.0f) : sqrtf(fmaxf(sqs[r] + ne, 0.0f));
    float h  = fmaxf(ap - an + MARGIN, 0.0f);
    double s = (double)h;
#pragma unroll
    for (int m = 1; m < 64; m <<= 1) s += __shfl_xor(s, m, 64);
    __shared__ double sh[4];
    if ((threadIdx.x & 63) == 0) sh[threadIdx.x >> 6] = s;
    __syncthreads();
    if (threadIdx.x == 0) {
        double b = sh[0] + sh[1] + sh[2] + sh[3];
        atomicAdd(accd, b);
        __threadfence();
        unsigned old = atomicAdd(ticket, 1u);
        if (old == gridDim.x - 1) {
            double total = atomicAdd(accd, 0.0);  // coherent read
            out[0] = (float)(total / (double)NROWS);
        }
    }
}

extern "C" void kernel_launch(void* const* d_in, const int* in_sizes, int n_in,
                              void* d_out, int out_size, void* d_ws, size_t ws_size,
                              hipStream_t stream) {
    const float* in  = (const float*)d_in[0];
    const int*   tgt = (const int*)d_in[1];
    float*       out = (float*)d_out;

    char* ws = (char*)d_ws;
    ushort*   xbs    = (ushort*)(ws + XBS_OFF);
    float*    sqs    = (float*)(ws + SQS_OFF);
    int*      tgts   = (int*)(ws + TGT_OFF);
    unsigned* pmax   = (unsigned*)(ws + PMX_OFF);
    unsigned* nmin   = (unsigned*)(ws + NMN_OFF);
    int*      bincur = (int*)(ws + BIN_OFF);
    double*   accd   = (double*)(ws + ACC_OFF);
    unsigned* ticket = (unsigned*)(ws + TIK_OFF);

    hist_scan_kernel<<<1, 512, 0, stream>>>(tgt, bincur, accd, ticket);
    norm_scatter_kernel<<<NROWS / 4, 256, 0, stream>>>(in, tgt, bincur, xbs, sqs, tgts, pmax, nmin);
    gram_kernel<<<dim3(32, 16), 256, 0, stream>>>(xbs, sqs, tgts, pmax, nmin);
    finalize_kernel<<<32, 256, 0, stream>>>(pmax, nmin, sqs, accd, ticket, out);
}